// Round 1
// baseline (637.349 us; speedup 1.0000x reference)
//
#include <hip/hip_runtime.h>
#include <math.h>

// ---------------------------------------------------------------------------
// AFNO3D + LoRA,  B=4 H=W=L=64 C=64, modes kh<32 kw<32 kl<8, NB=8 BS=8 R=8
//
// Pipeline (all intermediates live INSIDE d_out, interleaved per 16KB region):
//   region p = (b*64+h)*64+w, region floats = 4096 (16KB)
//   byte sub-ranges per region (float2 offsets from p*2048):
//     z1 : [0    , 512 )  f2   (K6 out, K7 in)
//     y1 : [512  , 1024)  f2   (K1 out, K2 in)
//     y2 : [1024 , 1280)  f2 per region chunk (K2 out, K3 in)
//     y3 : [1280 , 1408)  f2 per region chunk (K3 out, K4 in/out, K5 in)
//     z2 : [1408 , 1664)  f2 per region chunk (K5 out, K6 in)
//   K7 overwrites whole region with final output.
// ---------------------------------------------------------------------------

__device__ __forceinline__ void build_tw(float2* tw) {
    int t = threadIdx.x;
    if (t < 64) {
        float s, c;
        sincosf(0.09817477042468103f * (float)t, &s, &c);  // 2*pi*t/64
        tw[t] = make_float2(c, s);
    }
    __syncthreads();
}

__device__ __forceinline__ float gelu_exact(float t) {
    return 0.5f * t * (1.0f + erff(t * 0.7071067811865475f));
}

// K1: DFT along L (real -> 8 complex modes).  x[p][l][c] -> y1[p][kl][c]
__global__ void k1_dft_l(const float* __restrict__ x, float* __restrict__ buf) {
    __shared__ float2 tw[64];
    build_tw(tw);
    int tid = threadIdx.x;
    int c = tid & 63;
    int p = blockIdx.x * 4 + (tid >> 6);
    const float* xp = x + (size_t)p * 4096 + c;
    float ar[8], ai[8];
#pragma unroll
    for (int kl = 0; kl < 8; ++kl) { ar[kl] = 0.f; ai[kl] = 0.f; }
    for (int l = 0; l < 64; ++l) {
        float v = xp[l * 64];
#pragma unroll
        for (int kl = 0; kl < 8; ++kl) {
            float2 t = tw[(l * kl) & 63];
            ar[kl] += v * t.x;   // e^{-i th}: (c, -s)
            ai[kl] -= v * t.y;
        }
    }
    float2* y1 = (float2*)buf;
    size_t base = (size_t)p * 2048 + 512 + c;
#pragma unroll
    for (int kl = 0; kl < 8; ++kl)
        y1[base + kl * 64] = make_float2(ar[kl], ai[kl]);
}

// K2: DFT along W (64 -> 32 modes).  y1[(b,h,w)][kl][c] -> y2[(b,h,kw)][kl][c]
__global__ void k2_dft_w(float* __restrict__ buf) {
    __shared__ float2 tw[64];
    build_tw(tw);
    int tid = threadIdx.x;
    int c = tid & 63;
    int pos = blockIdx.x * 4 + (tid >> 6);   // (b*64+h)*8 + kl, 2048 total
    int kl = pos & 7;
    int bh = pos >> 3;
    float ar[32], ai[32];
#pragma unroll
    for (int kw = 0; kw < 32; ++kw) { ar[kw] = 0.f; ai[kw] = 0.f; }
    const float2* f2 = (const float2*)buf;
    for (int w = 0; w < 64; ++w) {
        float2 v = f2[(size_t)(bh * 64 + w) * 2048 + 512 + kl * 64 + c];
#pragma unroll
        for (int kw = 0; kw < 32; ++kw) {
            float2 t = tw[(w * kw) & 63];
            ar[kw] += v.x * t.x + v.y * t.y;   // (vr+ivi)*(c-is)
            ai[kw] += v.y * t.x - v.x * t.y;
        }
    }
    float2* out = (float2*)buf;
#pragma unroll
    for (int kw = 0; kw < 32; ++kw) {
        int idx = (bh * 32 + kw) * 512 + kl * 64 + c;
        out[(size_t)(idx >> 8) * 2048 + 1024 + (idx & 255)] = make_float2(ar[kw], ai[kw]);
    }
}

// K3: DFT along H (64 -> 32 modes), apply forward ortho scale 1/512.
// y2[(b,h,kw)][kl][c] -> y3[pos3=((b*32+kh)*32+kw)*8+kl][c]
__global__ void k3_dft_h(float* __restrict__ buf) {
    __shared__ float2 tw[64];
    build_tw(tw);
    int tid = threadIdx.x;
    int c = tid & 63;
    int pos = blockIdx.x * 4 + (tid >> 6);   // (b*32+kw)*8 + kl, 1024 total
    int kl = pos & 7;
    int kw = (pos >> 3) & 31;
    int b  = pos >> 8;
    float ar[32], ai[32];
#pragma unroll
    for (int kh = 0; kh < 32; ++kh) { ar[kh] = 0.f; ai[kh] = 0.f; }
    const float2* f2 = (const float2*)buf;
    for (int h = 0; h < 64; ++h) {
        int idx = ((b * 64 + h) * 32 + kw) * 512 + kl * 64 + c;
        float2 v = f2[(size_t)(idx >> 8) * 2048 + 1024 + (idx & 255)];
#pragma unroll
        for (int kh = 0; kh < 32; ++kh) {
            float2 t = tw[(h * kh) & 63];
            ar[kh] += v.x * t.x + v.y * t.y;
            ai[kh] += v.y * t.x - v.x * t.y;
        }
    }
    float2* out = (float2*)buf;
    const float sc = 1.0f / 512.0f;
#pragma unroll
    for (int kh = 0; kh < 32; ++kh) {
        int pos3 = ((b * 32 + kh) * 32 + kw) * 8 + kl;
        int idx = pos3 * 64 + c;
        out[(size_t)(idx >> 7) * 2048 + 1280 + (idx & 127)] =
            make_float2(ar[kh] * sc, ai[kh] * sc);
    }
}

// K4: block-diagonal complex MLP with LoRA weights, in place on y3.
__global__ void k4_mlp(float* __restrict__ buf,
                       const float* __restrict__ w1, const float* __restrict__ b1,
                       const float* __restrict__ w2, const float* __restrict__ b2,
                       const float* __restrict__ la1rA, const float* __restrict__ la1rB,
                       const float* __restrict__ la1iA, const float* __restrict__ la1iB,
                       const float* __restrict__ la2rA, const float* __restrict__ la2rB,
                       const float* __restrict__ la2iA, const float* __restrict__ la2iB) {
    __shared__ float sW[4][512];   // [mat][(i*8+o)*8 + n]  (n innermost: no bank conflict)
    __shared__ float sb1[128];     // [e*64 + n*8 + o]
    __shared__ float sb2[128];
    int tid = threadIdx.x;
    const float* As[4]   = {la1rA, la1iA, la2rA, la2iA};
    const float* Bs[4]   = {la1rB, la1iB, la2rB, la2iB};
    const float* base[4] = {w1, w1 + 512, w2, w2 + 512};
#pragma unroll
    for (int e = 0; e < 8; ++e) {
        int flat = tid + e * 256;    // 0..2047
        int mat = flat >> 9;
        int rem = flat & 511;
        int n = rem >> 6, i = (rem >> 3) & 7, o = rem & 7;
        const float* A  = As[mat] + n * 64 + i * 8;
        const float* Bp = Bs[mat] + n * 64 + o;
        float s = 0.f;
#pragma unroll
        for (int r = 0; r < 8; ++r) s += A[r] * Bp[r * 8];
        sW[mat][(i * 8 + o) * 8 + n] = base[mat][n * 64 + i * 8 + o] + 0.125f * s;
    }
    if (tid < 128) sb1[tid] = b1[tid];
    else           sb2[tid - 128] = b2[tid - 128];
    __syncthreads();

    int pair = blockIdx.x * 256 + tid;      // 262144 total
    int pos3 = pair >> 3, n = pair & 7;
    float2* f2 = (float2*)buf;
    int idx0 = pos3 * 64 + n * 8;
    float xr[8], xi[8];
#pragma unroll
    for (int i = 0; i < 8; ++i) {
        int idx = idx0 + i;
        float2 v = f2[(size_t)(idx >> 7) * 2048 + 1280 + (idx & 127)];
        xr[i] = v.x; xi[i] = v.y;
    }
    float o1r[8], o1i[8];
#pragma unroll
    for (int o = 0; o < 8; ++o) {
        float br = sb1[n * 8 + o], bi = sb1[64 + n * 8 + o];
        float sr = br - bi;
        float si = br + bi;
#pragma unroll
        for (int i = 0; i < 8; ++i) {
            float wr = sW[0][(i * 8 + o) * 8 + n];
            float wi = sW[1][(i * 8 + o) * 8 + n];
            sr += xr[i] * wr - xi[i] * wi;
            si += xi[i] * wr + xr[i] * wi;
        }
        o1r[o] = gelu_exact(sr);
        o1i[o] = gelu_exact(si);
    }
#pragma unroll
    for (int o = 0; o < 8; ++o) {
        float br = sb2[n * 8 + o], bi = sb2[64 + n * 8 + o];
        float sr = br - bi;
        float si = br + bi;
#pragma unroll
        for (int i = 0; i < 8; ++i) {
            float wr = sW[2][(i * 8 + o) * 8 + n];
            float wi = sW[3][(i * 8 + o) * 8 + n];
            sr += o1r[i] * wr - o1i[i] * wi;
            si += o1i[i] * wr + o1r[i] * wi;
        }
        int idx = idx0 + o;
        f2[(size_t)(idx >> 7) * 2048 + 1280 + (idx & 127)] = make_float2(sr, si);
    }
}

// K5: inverse DFT along H (32 modes -> 64).  y3 -> z2[(b,h,kw)][kl][c]
__global__ void k5_idft_h(float* __restrict__ buf) {
    __shared__ float2 tw[64];
    build_tw(tw);
    int tid = threadIdx.x;
    int c = tid & 63;
    int pos = blockIdx.x * 4 + (tid >> 6);   // (b*32+kw)*8 + kl, 1024 total
    int kl = pos & 7;
    int kw = (pos >> 3) & 31;
    int b  = pos >> 8;
    const float2* f2 = (const float2*)buf;
    float inr[32], ini[32];
#pragma unroll
    for (int kh = 0; kh < 32; ++kh) {
        int idx = (((b * 32 + kh) * 32 + kw) * 8 + kl) * 64 + c;
        float2 v = f2[(size_t)(idx >> 7) * 2048 + 1280 + (idx & 127)];
        inr[kh] = v.x; ini[kh] = v.y;
    }
    float2* out = (float2*)buf;
    for (int h = 0; h < 64; ++h) {
        float ar = 0.f, ai = 0.f;
#pragma unroll
        for (int kh = 0; kh < 32; ++kh) {
            float2 t = tw[(h * kh) & 63];
            ar += inr[kh] * t.x - ini[kh] * t.y;   // e^{+i th}
            ai += ini[kh] * t.x + inr[kh] * t.y;
        }
        int idx = ((b * 64 + h) * 32 + kw) * 512 + kl * 64 + c;
        out[(size_t)(idx >> 8) * 2048 + 1408 + (idx & 255)] = make_float2(ar, ai);
    }
}

// K6: inverse DFT along W (32 modes -> 64).  z2 -> z1[(b,h,w)][kl][c]
__global__ void k6_idft_w(float* __restrict__ buf) {
    __shared__ float2 tw[64];
    build_tw(tw);
    int tid = threadIdx.x;
    int c = tid & 63;
    int pos = blockIdx.x * 4 + (tid >> 6);   // (b*64+h)*8 + kl, 2048 total
    int kl = pos & 7;
    int bh = pos >> 3;
    const float2* f2 = (const float2*)buf;
    float inr[32], ini[32];
#pragma unroll
    for (int kw = 0; kw < 32; ++kw) {
        int idx = (bh * 32 + kw) * 512 + kl * 64 + c;
        float2 v = f2[(size_t)(idx >> 8) * 2048 + 1408 + (idx & 255)];
        inr[kw] = v.x; ini[kw] = v.y;
    }
    float2* out = (float2*)buf;
    for (int w = 0; w < 64; ++w) {
        float ar = 0.f, ai = 0.f;
#pragma unroll
        for (int kw = 0; kw < 32; ++kw) {
            float2 t = tw[(w * kw) & 63];
            ar += inr[kw] * t.x - ini[kw] * t.y;
            ai += ini[kw] * t.x + inr[kw] * t.y;
        }
        out[(size_t)(bh * 64 + w) * 2048 + kl * 64 + c] = make_float2(ar, ai);
    }
}

// K7: inverse rfft along L (8 half-modes -> 64 real, numpy irfft semantics:
// Im of kl=0 dropped), ortho scale 1/512, + residual x. Overwrites region.
__global__ void k7_irfft_l(const float* __restrict__ x, float* __restrict__ buf) {
    __shared__ float2 tw[64];
    build_tw(tw);
    int tid = threadIdx.x;
    int c = tid & 63;
    int p = blockIdx.x * 4 + (tid >> 6);
    const float2* z = (const float2*)buf;
    float zr[8], zi[8];
#pragma unroll
    for (int kl = 0; kl < 8; ++kl) {
        float2 v = z[(size_t)p * 2048 + kl * 64 + c];
        zr[kl] = v.x; zi[kl] = v.y;
    }
    const float* xp = x + (size_t)p * 4096 + c;
    float* op = buf + (size_t)p * 4096 + c;
    const float sc = 1.0f / 512.0f;
    for (int l = 0; l < 64; ++l) {
        float s = zr[0];
#pragma unroll
        for (int kl = 1; kl < 8; ++kl) {
            float2 t = tw[(l * kl) & 63];
            s += 2.0f * (zr[kl] * t.x - zi[kl] * t.y);
        }
        op[l * 64] = s * sc + xp[l * 64];
    }
}

extern "C" void kernel_launch(void* const* d_in, const int* in_sizes, int n_in,
                              void* d_out, int out_size, void* d_ws, size_t ws_size,
                              hipStream_t stream) {
    const float* x     = (const float*)d_in[0];
    const float* w1    = (const float*)d_in[1];
    const float* b1    = (const float*)d_in[2];
    const float* w2    = (const float*)d_in[3];
    const float* b2    = (const float*)d_in[4];
    const float* la1rA = (const float*)d_in[5];
    const float* la1rB = (const float*)d_in[6];
    const float* la1iA = (const float*)d_in[7];
    const float* la1iB = (const float*)d_in[8];
    const float* la2rA = (const float*)d_in[9];
    const float* la2rB = (const float*)d_in[10];
    const float* la2iA = (const float*)d_in[11];
    const float* la2iB = (const float*)d_in[12];
    float* out = (float*)d_out;

    hipLaunchKernelGGL(k1_dft_l,  dim3(4096), dim3(256), 0, stream, x, out);
    hipLaunchKernelGGL(k2_dft_w,  dim3(512),  dim3(256), 0, stream, out);
    hipLaunchKernelGGL(k3_dft_h,  dim3(256),  dim3(256), 0, stream, out);
    hipLaunchKernelGGL(k4_mlp,    dim3(1024), dim3(256), 0, stream, out,
                       w1, b1, w2, b2, la1rA, la1rB, la1iA, la1iB,
                       la2rA, la2rB, la2iA, la2iB);
    hipLaunchKernelGGL(k5_idft_h, dim3(256),  dim3(256), 0, stream, out);
    hipLaunchKernelGGL(k6_idft_w, dim3(512),  dim3(256), 0, stream, out);
    hipLaunchKernelGGL(k7_irfft_l, dim3(4096), dim3(256), 0, stream, x, out);
}

// Round 2
// 446.393 us; speedup vs baseline: 1.4278x; 1.4278x over previous
//
#include <hip/hip_runtime.h>
#include <math.h>

// ---------------------------------------------------------------------------
// AFNO3D + LoRA, B=4 H=W=L=64 C=64, modes kh<32 kw<32 kl<8, NB=8 BS=8 R=8.
//
// 5-kernel pipeline, intermediates in d_ws (1 GiB available; we use 201 MB):
//   KA: x[p][l][c]            -> y1[p][kl][c]           (DFT-L, 8 modes)
//   KB: y1                     -> y2[b][kl][kw][h][c]    (DFT-W, 32 modes)
//   KC: y2 -> (DFT-H + MLP + iDFT-H fused in LDS) -> z2[b][kl][kw][h][c]
//   KD: z2                     -> z1[p][kl][c]           (iDFT-W)
//   KE: z1 + x                 -> out                    (iDFT-L + residual)
// p = (b*64+h)*64+w. All complex stored as float2. fp32 throughout.
// Ortho scaling: 1/512 applied in KC (pre-MLP) and in KE.
// ---------------------------------------------------------------------------

#define PI2_64 0.09817477042468103f   // 2*pi/64

__device__ __forceinline__ void build_tw(float2* tw) {
    int t = threadIdx.x;
    if (t < 64) {
        float s, c;
        sincosf(PI2_64 * (float)t, &s, &c);
        tw[t] = make_float2(c, s);
    }
    __syncthreads();
}

__device__ __forceinline__ float gelu_exact(float t) {
    return 0.5f * t * (1.0f + erff(t * 0.7071067811865475f));
}

// ===========================================================================
// KA: DFT along L (real -> 8 complex modes), float4 over c.
// thread = (p = blk*16 + tid>>4, c4 = tid&15), covers c = 4*c4 .. +3
__global__ void __launch_bounds__(256) ka_dft_l(const float* __restrict__ x,
                                                float* __restrict__ y1f) {
    __shared__ float2 tw[64];
    build_tw(tw);
    int tid = threadIdx.x;
    int c4 = tid & 15;
    int p  = blockIdx.x * 16 + (tid >> 4);
    const float4* xp = (const float4*)(x + (size_t)p * 4096) + c4;
    float ar[8][4], ai[8][4];
#pragma unroll
    for (int kl = 0; kl < 8; ++kl)
#pragma unroll
        for (int j = 0; j < 4; ++j) { ar[kl][j] = 0.f; ai[kl][j] = 0.f; }
    for (int l = 0; l < 64; ++l) {
        float4 v = xp[l * 16];
        float vv[4] = {v.x, v.y, v.z, v.w};
#pragma unroll
        for (int kl = 0; kl < 8; ++kl) {
            float2 t = tw[(l * kl) & 63];
#pragma unroll
            for (int j = 0; j < 4; ++j) {
                ar[kl][j] += vv[j] * t.x;   // e^{-i th} = (c, -s)
                ai[kl][j] -= vv[j] * t.y;
            }
        }
    }
    float2* y1 = (float2*)y1f;
    size_t base = (size_t)p * 512 + c4 * 4;
#pragma unroll
    for (int kl = 0; kl < 8; ++kl) {
        float4* o = (float4*)(y1 + base + kl * 64);
        o[0] = make_float4(ar[kl][0], ai[kl][0], ar[kl][1], ai[kl][1]);
        o[1] = make_float4(ar[kl][2], ai[kl][2], ar[kl][3], ai[kl][3]);
    }
}

// ===========================================================================
// KB: DFT along W (64 -> 32 modes). Block handles 2 positions (b,h,kl).
// LDS-tiled complex GEMM: C[kw][c] = sum_w T[w][kw] * D[w][c].
__global__ void __launch_bounds__(256) kb_dft_w(const float* __restrict__ y1f,
                                                float* __restrict__ y2f) {
    __shared__ float2 sD[2][64][64];   // 64 KB
    __shared__ float2 sU[64][32];      // 16 KB,  e^{-2pi i w*kw/64} at [w][kw]
    int tid = threadIdx.x;
#pragma unroll
    for (int r = 0; r < 8; ++r) {
        int idx = r * 256 + tid;
        int w = idx >> 5, kw = idx & 31;
        float sn, cs;
        sincosf(PI2_64 * (float)((w * kw) & 63), &sn, &cs);
        sU[w][kw] = make_float2(cs, -sn);
    }
    const float2* y1 = (const float2*)y1f;
#pragma unroll
    for (int q = 0; q < 2; ++q) {
        int pos = blockIdx.x * 2 + q;       // (b*64+h)*8 + kl
        int kl = pos & 7, bh = pos >> 3;
#pragma unroll
        for (int r = 0; r < 8; ++r) {
            int f = r * 512 + tid * 2;      // f2 index in [0,4096)
            int w = f >> 6, c = f & 63;
            float4 v = *(const float4*)(y1 + (size_t)(bh * 64 + w) * 512 + kl * 64 + c);
            *(float4*)(&sD[q][w][c]) = v;
        }
    }
    __syncthreads();
    int q = tid >> 7, t = tid & 127;
    int kw0 = (t >> 4) * 4;
    int c0  = (t & 15) * 4;
    float acr[4][4], aci[4][4];
#pragma unroll
    for (int i = 0; i < 4; ++i)
#pragma unroll
        for (int j = 0; j < 4; ++j) { acr[i][j] = 0.f; aci[i][j] = 0.f; }
    for (int w = 0; w < 64; ++w) {
        const float4* tU = (const float4*)(&sU[w][kw0]);
        float4 u0 = tU[0], u1 = tU[1];
        const float4* tD = (const float4*)(&sD[q][w][c0]);
        float4 d0 = tD[0], d1 = tD[1];
        float Tr[4] = {u0.x, u0.z, u1.x, u1.z};
        float Ti[4] = {u0.y, u0.w, u1.y, u1.w};
        float Dr[4] = {d0.x, d0.z, d1.x, d1.z};
        float Di[4] = {d0.y, d0.w, d1.y, d1.w};
#pragma unroll
        for (int i = 0; i < 4; ++i)
#pragma unroll
            for (int j = 0; j < 4; ++j) {
                acr[i][j] += Tr[i] * Dr[j] - Ti[i] * Di[j];
                aci[i][j] += Tr[i] * Di[j] + Ti[i] * Dr[j];
            }
    }
    int pos = blockIdx.x * 2 + q;
    int kl = pos & 7, bh = pos >> 3;
    int b = bh >> 6, h = bh & 63;
    float2* y2 = (float2*)y2f;
#pragma unroll
    for (int i = 0; i < 4; ++i) {
        size_t o = ((size_t)((b * 8 + kl) * 32 + (kw0 + i)) * 64 + h) * 64 + c0;
        float4* dst = (float4*)(y2 + o);
        dst[0] = make_float4(acr[i][0], aci[i][0], acr[i][1], aci[i][1]);
        dst[1] = make_float4(acr[i][2], aci[i][2], acr[i][3], aci[i][3]);
    }
}

// ===========================================================================
// KC: fused DFT-H (64->32, *1/512) + block-diag complex MLP + iDFT-H (32->64).
// One block per (b,kw,kl). Data lives in LDS the whole time.
__global__ void __launch_bounds__(256) kc_h_mlp(
        const float* __restrict__ y2f, float* __restrict__ z2f,
        const float* __restrict__ w1, const float* __restrict__ b1,
        const float* __restrict__ w2, const float* __restrict__ b2,
        const float* __restrict__ la1rA, const float* __restrict__ la1rB,
        const float* __restrict__ la1iA, const float* __restrict__ la1iB,
        const float* __restrict__ la2rA, const float* __restrict__ la2rB,
        const float* __restrict__ la2iA, const float* __restrict__ la2iB) {
    __shared__ float2 sD[64][64];      // 32 KB staged input; reused as sM2[32][66]
    __shared__ float2 sT[64][34];      // 17 KB, e^{-2pi i h*kh/64} at [h][kh] (kh<32)
    __shared__ float2 sM[32][66];      // 16.9 KB
    __shared__ float  sW[4][512];
    __shared__ float  sb1[128], sb2[128];
    int tid = threadIdx.x;
    int pos = blockIdx.x;              // (b*32+kw)*8 + kl
    int kl = pos & 7, kw = (pos >> 3) & 31, b = pos >> 8;

#pragma unroll
    for (int r = 0; r < 8; ++r) {
        int idx = r * 256 + tid;
        int h = idx >> 5, kh = idx & 31;
        float sn, cs;
        sincosf(PI2_64 * (float)((h * kh) & 63), &sn, &cs);
        sT[h][kh] = make_float2(cs, -sn);
    }
    const float2* src = (const float2*)y2f + (size_t)((b * 8 + kl) * 32 + kw) * 4096;
#pragma unroll
    for (int r = 0; r < 8; ++r) {
        int f = r * 512 + tid * 2;
        *(float4*)(&sD[f >> 6][f & 63]) = *(const float4*)(src + f);
    }
    {   // LoRA-corrected weights (same as validated K4)
        const float* As[4]   = {la1rA, la1iA, la2rA, la2iA};
        const float* Bs[4]   = {la1rB, la1iB, la2rB, la2iB};
        const float* base[4] = {w1, w1 + 512, w2, w2 + 512};
#pragma unroll
        for (int e = 0; e < 8; ++e) {
            int flat = tid + e * 256;
            int mat = flat >> 9;
            int rem = flat & 511;
            int n = rem >> 6, i = (rem >> 3) & 7, o = rem & 7;
            const float* A  = As[mat] + n * 64 + i * 8;
            const float* Bp = Bs[mat] + n * 64 + o;
            float s = 0.f;
#pragma unroll
            for (int r = 0; r < 8; ++r) s += A[r] * Bp[r * 8];
            sW[mat][(i * 8 + o) * 8 + n] = base[mat][n * 64 + i * 8 + o] + 0.125f * s;
        }
        if (tid < 128) sb1[tid] = b1[tid];
        else           sb2[tid - 128] = b2[tid - 128];
    }
    __syncthreads();

    // ---- M[kh][c] = (1/512) * sum_h T[h][kh] * D[h][c], tile 4kh x 2c ----
    {
        int kh0 = (tid >> 5) * 4;
        int c0  = (tid & 31) * 2;
        float mr[4][2], mi[4][2];
#pragma unroll
        for (int i = 0; i < 4; ++i)
#pragma unroll
            for (int j = 0; j < 2; ++j) { mr[i][j] = 0.f; mi[i][j] = 0.f; }
        for (int h = 0; h < 64; ++h) {
            const float4* tT = (const float4*)(&sT[h][kh0]);
            float4 u0 = tT[0], u1 = tT[1];
            float4 d0 = *(const float4*)(&sD[h][c0]);
            float Tr[4] = {u0.x, u0.z, u1.x, u1.z};
            float Ti[4] = {u0.y, u0.w, u1.y, u1.w};
            float Dr[2] = {d0.x, d0.z};
            float Di[2] = {d0.y, d0.w};
#pragma unroll
            for (int i = 0; i < 4; ++i)
#pragma unroll
                for (int j = 0; j < 2; ++j) {
                    mr[i][j] += Tr[i] * Dr[j] - Ti[i] * Di[j];
                    mi[i][j] += Tr[i] * Di[j] + Ti[i] * Dr[j];
                }
        }
        const float sc = 1.0f / 512.0f;
#pragma unroll
        for (int i = 0; i < 4; ++i)
#pragma unroll
            for (int j = 0; j < 2; ++j)
                sM[kh0 + i][c0 + j] = make_float2(mr[i][j] * sc, mi[i][j] * sc);
    }
    __syncthreads();

    // ---- MLP per (kh, n): identical math to validated K4 ----
    float2* sM2 = (float2*)&sD[0][0];   // [32][66]
    {
        int kh = tid >> 3, n = tid & 7;
        float xr[8], xi[8];
#pragma unroll
        for (int i = 0; i < 8; ++i) {
            float2 v = sM[kh][n * 8 + i];
            xr[i] = v.x; xi[i] = v.y;
        }
        float o1r[8], o1i[8];
#pragma unroll
        for (int o = 0; o < 8; ++o) {
            float br = sb1[n * 8 + o], bi = sb1[64 + n * 8 + o];
            float sr = br - bi, si = br + bi;
#pragma unroll
            for (int i = 0; i < 8; ++i) {
                float wr = sW[0][(i * 8 + o) * 8 + n];
                float wi = sW[1][(i * 8 + o) * 8 + n];
                sr += xr[i] * wr - xi[i] * wi;
                si += xi[i] * wr + xr[i] * wi;
            }
            o1r[o] = gelu_exact(sr);
            o1i[o] = gelu_exact(si);
        }
#pragma unroll
        for (int o = 0; o < 8; ++o) {
            float br = sb2[n * 8 + o], bi = sb2[64 + n * 8 + o];
            float sr = br - bi, si = br + bi;
#pragma unroll
            for (int i = 0; i < 8; ++i) {
                float wr = sW[2][(i * 8 + o) * 8 + n];
                float wi = sW[3][(i * 8 + o) * 8 + n];
                sr += o1r[i] * wr - o1i[i] * wi;
                si += o1i[i] * wr + o1r[i] * wi;
            }
            sM2[kh * 66 + n * 8 + o] = make_float2(sr, si);
        }
    }
    __syncthreads();

    // ---- out[h][c] = sum_kh conj(T[h][kh]) * M2[kh][c], tile 4h x 4c ----
    {
        int h0 = (tid >> 4) * 4;
        int c0 = (tid & 15) * 4;
        float orr[4][4], oii[4][4];
#pragma unroll
        for (int i = 0; i < 4; ++i)
#pragma unroll
            for (int j = 0; j < 4; ++j) { orr[i][j] = 0.f; oii[i][j] = 0.f; }
        for (int kh = 0; kh < 32; ++kh) {
            float2 T0 = sT[h0 + 0][kh];
            float2 T1 = sT[h0 + 1][kh];
            float2 T2 = sT[h0 + 2][kh];
            float2 T3 = sT[h0 + 3][kh];
            float Tr[4] = {T0.x, T1.x, T2.x, T3.x};
            float Ti[4] = {T0.y, T1.y, T2.y, T3.y};
            const float4* tM = (const float4*)(sM2 + kh * 66 + c0);
            float4 m0 = tM[0], m1 = tM[1];
            float Mr[4] = {m0.x, m0.z, m1.x, m1.z};
            float Mi[4] = {m0.y, m0.w, m1.y, m1.w};
#pragma unroll
            for (int i = 0; i < 4; ++i)
#pragma unroll
                for (int j = 0; j < 4; ++j) {
                    // conj(T)=(Tr,-Ti) stored with Ti=-sin -> conj = (Tr, +sin)
                    orr[i][j] += Tr[i] * Mr[j] + Ti[i] * Mi[j];
                    oii[i][j] += Tr[i] * Mi[j] - Ti[i] * Mr[j];
                }
        }
        float2* dst = (float2*)z2f + (size_t)((b * 8 + kl) * 32 + kw) * 4096;
#pragma unroll
        for (int i = 0; i < 4; ++i) {
            float4* d4 = (float4*)(dst + (h0 + i) * 64 + c0);
            d4[0] = make_float4(orr[i][0], oii[i][0], orr[i][1], oii[i][1]);
            d4[1] = make_float4(orr[i][2], oii[i][2], orr[i][3], oii[i][3]);
        }
    }
}

// ===========================================================================
// KD: iDFT along W (32 modes -> 64). Block handles 2 positions (b,h,kl).
// C[w][c] = sum_kw U[kw][w] * M[kw][c], U = e^{+2pi i w*kw/64}. Tile 4w x 8c.
__global__ void __launch_bounds__(256) kd_idft_w(const float* __restrict__ z2f,
                                                 float* __restrict__ z1f) {
    __shared__ float2 sM[2][32][64];   // 32 KB
    __shared__ float2 sU[32][64];      // 16 KB, [kw][w]
    int tid = threadIdx.x;
#pragma unroll
    for (int r = 0; r < 8; ++r) {
        int idx = r * 256 + tid;
        int kw = idx >> 6, w = idx & 63;
        float sn, cs;
        sincosf(PI2_64 * (float)((w * kw) & 63), &sn, &cs);
        sU[kw][w] = make_float2(cs, sn);
    }
    const float2* z2 = (const float2*)z2f;
#pragma unroll
    for (int q = 0; q < 2; ++q) {
        int pos = blockIdx.x * 2 + q;     // (b*64+h)*8 + kl
        int kl = pos & 7, bh = pos >> 3;
        int b = bh >> 6, h = bh & 63;
        const float2* base = z2 + ((size_t)(b * 8 + kl) * 32 * 64 + h) * 64;
#pragma unroll
        for (int r = 0; r < 4; ++r) {
            int f = r * 512 + tid * 2;    // f2 index in [0,2048)
            int kw = f >> 6, c = f & 63;
            *(float4*)(&sM[q][kw][c]) = *(const float4*)(base + (size_t)kw * 4096 + c);
        }
    }
    __syncthreads();
    int q = tid >> 7, t = tid & 127;
    int w0 = (t >> 3) * 4;
    int c0 = (t & 7) * 8;
    float ar[4][8], ai[4][8];
#pragma unroll
    for (int i = 0; i < 4; ++i)
#pragma unroll
        for (int j = 0; j < 8; ++j) { ar[i][j] = 0.f; ai[i][j] = 0.f; }
    for (int kw = 0; kw < 32; ++kw) {
        const float4* tU = (const float4*)(&sU[kw][w0]);
        float4 u0 = tU[0], u1 = tU[1];
        const float4* tM = (const float4*)(&sM[q][kw][c0]);
        float4 m0 = tM[0], m1 = tM[1], m2 = tM[2], m3 = tM[3];
        float Ur[4] = {u0.x, u0.z, u1.x, u1.z};
        float Ui[4] = {u0.y, u0.w, u1.y, u1.w};
        float Mr[8] = {m0.x, m0.z, m1.x, m1.z, m2.x, m2.z, m3.x, m3.z};
        float Mi[8] = {m0.y, m0.w, m1.y, m1.w, m2.y, m2.w, m3.y, m3.w};
#pragma unroll
        for (int i = 0; i < 4; ++i)
#pragma unroll
            for (int j = 0; j < 8; ++j) {
                ar[i][j] += Ur[i] * Mr[j] - Ui[i] * Mi[j];
                ai[i][j] += Ur[i] * Mi[j] + Ui[i] * Mr[j];
            }
    }
    int pos = blockIdx.x * 2 + q;
    int kl = pos & 7, bh = pos >> 3;
    float2* z1 = (float2*)z1f;
#pragma unroll
    for (int i = 0; i < 4; ++i) {
        size_t o = (size_t)(bh * 64 + (w0 + i)) * 512 + kl * 64 + c0;
        float4* dst = (float4*)(z1 + o);
        dst[0] = make_float4(ar[i][0], ai[i][0], ar[i][1], ai[i][1]);
        dst[1] = make_float4(ar[i][2], ai[i][2], ar[i][3], ai[i][3]);
        dst[2] = make_float4(ar[i][4], ai[i][4], ar[i][5], ai[i][5]);
        dst[3] = make_float4(ar[i][6], ai[i][6], ar[i][7], ai[i][7]);
    }
}

// ===========================================================================
// KE: inverse rfft along L (numpy irfft semantics: Im(kl=0) dropped, modes
// 1..7 doubled), *1/512, + residual x. float4 over c.
__global__ void __launch_bounds__(256) ke_idft_l(const float* __restrict__ x,
                                                 const float* __restrict__ z1f,
                                                 float* __restrict__ out) {
    __shared__ float2 tw[64];
    build_tw(tw);
    int tid = threadIdx.x;
    int c4 = tid & 15;
    int p  = blockIdx.x * 16 + (tid >> 4);
    const float2* z = (const float2*)z1f + (size_t)p * 512 + c4 * 4;
    float zr[8][4], zi[8][4];
#pragma unroll
    for (int kl = 0; kl < 8; ++kl) {
        float4 a  = *(const float4*)(z + kl * 64);
        float4 b2 = *(const float4*)(z + kl * 64 + 2);
        zr[kl][0] = a.x;  zi[kl][0] = a.y;
        zr[kl][1] = a.z;  zi[kl][1] = a.w;
        zr[kl][2] = b2.x; zi[kl][2] = b2.y;
        zr[kl][3] = b2.z; zi[kl][3] = b2.w;
    }
    const float4* xp = (const float4*)(x + (size_t)p * 4096) + c4;
    float4* op = (float4*)(out + (size_t)p * 4096) + c4;
    const float sc = 1.0f / 512.0f;
    for (int l = 0; l < 64; ++l) {
        float s0 = zr[0][0], s1 = zr[0][1], s2 = zr[0][2], s3 = zr[0][3];
#pragma unroll
        for (int kl = 1; kl < 8; ++kl) {
            float2 t = tw[(l * kl) & 63];
            s0 += 2.0f * (zr[kl][0] * t.x - zi[kl][0] * t.y);
            s1 += 2.0f * (zr[kl][1] * t.x - zi[kl][1] * t.y);
            s2 += 2.0f * (zr[kl][2] * t.x - zi[kl][2] * t.y);
            s3 += 2.0f * (zr[kl][3] * t.x - zi[kl][3] * t.y);
        }
        float4 xv = xp[l * 16];
        op[l * 16] = make_float4(s0 * sc + xv.x, s1 * sc + xv.y,
                                 s2 * sc + xv.z, s3 * sc + xv.w);
    }
}

// ===========================================================================
extern "C" void kernel_launch(void* const* d_in, const int* in_sizes, int n_in,
                              void* d_out, int out_size, void* d_ws, size_t ws_size,
                              hipStream_t stream) {
    const float* x     = (const float*)d_in[0];
    const float* w1    = (const float*)d_in[1];
    const float* b1    = (const float*)d_in[2];
    const float* w2    = (const float*)d_in[3];
    const float* b2    = (const float*)d_in[4];
    const float* la1rA = (const float*)d_in[5];
    const float* la1rB = (const float*)d_in[6];
    const float* la1iA = (const float*)d_in[7];
    const float* la1iB = (const float*)d_in[8];
    const float* la2rA = (const float*)d_in[9];
    const float* la2rB = (const float*)d_in[10];
    const float* la2iA = (const float*)d_in[11];
    const float* la2iB = (const float*)d_in[12];
    float* out = (float*)d_out;

    float* ws = (float*)d_ws;
    float* y1 = ws;                    // [16384][8][64] f2  = 16777216 floats
    float* y2 = ws + 16777216;         // [4][8][32][64][64] f2 = 8388608 floats
    float* z2 = ws + 25165824;         // same shape as y2
    float* z1 = ws + 33554432;         // same shape as y1

    hipLaunchKernelGGL(ka_dft_l,  dim3(1024), dim3(256), 0, stream, x, y1);
    hipLaunchKernelGGL(kb_dft_w,  dim3(1024), dim3(256), 0, stream, y1, y2);
    hipLaunchKernelGGL(kc_h_mlp,  dim3(1024), dim3(256), 0, stream, y2, z2,
                       w1, b1, w2, b2, la1rA, la1rB, la1iA, la1iB,
                       la2rA, la2rB, la2iA, la2iB);
    hipLaunchKernelGGL(kd_idft_w, dim3(1024), dim3(256), 0, stream, z2, z1);
    hipLaunchKernelGGL(ke_idft_l, dim3(1024), dim3(256), 0, stream, x, z1, out);
}

// Round 3
// 363.150 us; speedup vs baseline: 1.7551x; 1.2292x over previous
//
#include <hip/hip_runtime.h>
#include <math.h>

// ---------------------------------------------------------------------------
// AFNO3D + LoRA, B=4 H=W=L=64 C=64, modes kh<32 kw<32 kl<8, NB=8 BS=8 R=8.
//
// 3-kernel pipeline (intermediates in d_ws, 32 MB used):
//   K1: per (b,h,c-half): DFT-L (real->8 modes) -> LDS slab -> DFT-W (->32)
//       writes y2[b][kl][kw][h][c]                      (320 MB traffic)
//   K2: per (b,kw,kl): DFT-H + block-diag complex MLP (LoRA) + iDFT-H, in LDS
//       y2 -> z2 (same layout)                          (128 MB traffic)
//   K3: per (b,h,c-half): stage z2 slab in LDS -> per-thread iDFT-W into
//       registers -> iDFT-L (numpy irfft semantics) + residual -> out
//                                                       (576 MB traffic)
// fp32 throughout. Ortho scaling: 1/512 in K2 (pre-MLP) and 1/512 in K3.
// Twiddle table tw[t] = (cos, sin) of 2*pi*t/64; forward DFT uses (c,-s),
// inverse uses (c,+s).
// ---------------------------------------------------------------------------

#define PI2_64 0.09817477042468103f   // 2*pi/64

__device__ __forceinline__ float gelu_exact(float t) {
    return 0.5f * t * (1.0f + erff(t * 0.7071067811865475f));
}

// ===========================================================================
// K1: fused DFT-L + DFT-W.  Block = (b, h, ch);  1024 threads.
// Phase 1: thread (w, cp): 64 l-reads of float2 (2 channels), 8 kl modes.
// LDS slab sY[kl][cp][w] (f4 = 2 complex), row stride 65 for bank spread.
// Phase 2: thread (kwq, kl, cp): reduce over w, write 4 kw outputs.
__global__ void __launch_bounds__(1024) k1_lw(const float* __restrict__ x,
                                              float* __restrict__ y2f) {
    __shared__ float2 tw[64];
    __shared__ float4 sY[8 * 16 * 65];   // 133120 B
    int tid = threadIdx.x;
    if (tid < 64) {
        float s, c;
        sincosf(PI2_64 * (float)tid, &s, &c);
        tw[tid] = make_float2(c, s);
    }
    __syncthreads();

    int bid = blockIdx.x;
    int b = bid >> 7, h = (bid >> 1) & 63, ch = bid & 1;
    int c0 = ch * 32;

    {   // ---- phase 1: DFT along L ----
        int cp = tid & 15, w = tid >> 4;
        const float* xp = x + ((size_t)((b * 64 + h) * 64 + w) * 64) * 64 + c0 + 2 * cp;
        float2 ar[8], ai[8];
#pragma unroll
        for (int kl = 0; kl < 8; ++kl) {
            ar[kl] = make_float2(0.f, 0.f);
            ai[kl] = make_float2(0.f, 0.f);
        }
        for (int l = 0; l < 64; ++l) {
            float2 v = *(const float2*)(xp + l * 64);
#pragma unroll
            for (int kl = 0; kl < 8; ++kl) {
                float2 t = tw[(l * kl) & 63];
                ar[kl].x += v.x * t.x;  ai[kl].x -= v.x * t.y;
                ar[kl].y += v.y * t.x;  ai[kl].y -= v.y * t.y;
            }
        }
#pragma unroll
        for (int kl = 0; kl < 8; ++kl)
            sY[(kl * 16 + cp) * 65 + w] =
                make_float4(ar[kl].x, ai[kl].x, ar[kl].y, ai[kl].y);
    }
    __syncthreads();

    {   // ---- phase 2: DFT along W (64 -> 32 modes) ----
        int cp = tid & 15, kl = (tid >> 4) & 7, kwq = tid >> 7;
        const float4* row = &sY[(kl * 16 + cp) * 65];
        float4 acc[4];
#pragma unroll
        for (int i = 0; i < 4; ++i) acc[i] = make_float4(0.f, 0.f, 0.f, 0.f);
        for (int w = 0; w < 64; ++w) {
            float4 d = row[w];
#pragma unroll
            for (int i = 0; i < 4; ++i) {
                int kw = kwq * 4 + i;
                float2 t = tw[(w * kw) & 63];
                acc[i].x += d.x * t.x + d.y * t.y;   // e^{-i th}
                acc[i].y += d.y * t.x - d.x * t.y;
                acc[i].z += d.z * t.x + d.w * t.y;
                acc[i].w += d.w * t.x - d.z * t.y;
            }
        }
        float4* y2 = (float4*)y2f;
#pragma unroll
        for (int i = 0; i < 4; ++i) {
            int kw = kwq * 4 + i;
            y2[(size_t)(((b * 8 + kl) * 32 + kw) * 64 + h) * 32 + ch * 16 + cp] = acc[i];
        }
    }
}

// ===========================================================================
// K2: fused DFT-H (64->32, *1/512) + block-diag complex MLP + iDFT-H (32->64).
// One block per (b,kw,kl). Validated in R2 (unchanged).
__global__ void __launch_bounds__(256) kc_h_mlp(
        const float* __restrict__ y2f, float* __restrict__ z2f,
        const float* __restrict__ w1, const float* __restrict__ b1,
        const float* __restrict__ w2, const float* __restrict__ b2,
        const float* __restrict__ la1rA, const float* __restrict__ la1rB,
        const float* __restrict__ la1iA, const float* __restrict__ la1iB,
        const float* __restrict__ la2rA, const float* __restrict__ la2rB,
        const float* __restrict__ la2iA, const float* __restrict__ la2iB) {
    __shared__ float2 sD[64][64];      // 32 KB staged input; reused as sM2[32][66]
    __shared__ float2 sT[64][34];      // e^{-2pi i h*kh/64} at [h][kh] (kh<32)
    __shared__ float2 sM[32][66];
    __shared__ float  sW[4][512];
    __shared__ float  sb1[128], sb2[128];
    int tid = threadIdx.x;
    int pos = blockIdx.x;              // (b*32+kw)*8 + kl
    int kl = pos & 7, kw = (pos >> 3) & 31, b = pos >> 8;

#pragma unroll
    for (int r = 0; r < 8; ++r) {
        int idx = r * 256 + tid;
        int h = idx >> 5, kh = idx & 31;
        float sn, cs;
        sincosf(PI2_64 * (float)((h * kh) & 63), &sn, &cs);
        sT[h][kh] = make_float2(cs, -sn);
    }
    const float2* src = (const float2*)y2f + (size_t)((b * 8 + kl) * 32 + kw) * 4096;
#pragma unroll
    for (int r = 0; r < 8; ++r) {
        int f = r * 512 + tid * 2;
        *(float4*)(&sD[f >> 6][f & 63]) = *(const float4*)(src + f);
    }
    {   // LoRA-corrected weights
        const float* As[4]   = {la1rA, la1iA, la2rA, la2iA};
        const float* Bs[4]   = {la1rB, la1iB, la2rB, la2iB};
        const float* base[4] = {w1, w1 + 512, w2, w2 + 512};
#pragma unroll
        for (int e = 0; e < 8; ++e) {
            int flat = tid + e * 256;
            int mat = flat >> 9;
            int rem = flat & 511;
            int n = rem >> 6, i = (rem >> 3) & 7, o = rem & 7;
            const float* A  = As[mat] + n * 64 + i * 8;
            const float* Bp = Bs[mat] + n * 64 + o;
            float s = 0.f;
#pragma unroll
            for (int r = 0; r < 8; ++r) s += A[r] * Bp[r * 8];
            sW[mat][(i * 8 + o) * 8 + n] = base[mat][n * 64 + i * 8 + o] + 0.125f * s;
        }
        if (tid < 128) sb1[tid] = b1[tid];
        else           sb2[tid - 128] = b2[tid - 128];
    }
    __syncthreads();

    // ---- M[kh][c] = (1/512) * sum_h T[h][kh] * D[h][c], tile 4kh x 2c ----
    {
        int kh0 = (tid >> 5) * 4;
        int c0  = (tid & 31) * 2;
        float mr[4][2], mi[4][2];
#pragma unroll
        for (int i = 0; i < 4; ++i)
#pragma unroll
            for (int j = 0; j < 2; ++j) { mr[i][j] = 0.f; mi[i][j] = 0.f; }
        for (int h = 0; h < 64; ++h) {
            const float4* tT = (const float4*)(&sT[h][kh0]);
            float4 u0 = tT[0], u1 = tT[1];
            float4 d0 = *(const float4*)(&sD[h][c0]);
            float Tr[4] = {u0.x, u0.z, u1.x, u1.z};
            float Ti[4] = {u0.y, u0.w, u1.y, u1.w};
            float Dr[2] = {d0.x, d0.z};
            float Di[2] = {d0.y, d0.w};
#pragma unroll
            for (int i = 0; i < 4; ++i)
#pragma unroll
                for (int j = 0; j < 2; ++j) {
                    mr[i][j] += Tr[i] * Dr[j] - Ti[i] * Di[j];
                    mi[i][j] += Tr[i] * Di[j] + Ti[i] * Dr[j];
                }
        }
        const float sc = 1.0f / 512.0f;
#pragma unroll
        for (int i = 0; i < 4; ++i)
#pragma unroll
            for (int j = 0; j < 2; ++j)
                sM[kh0 + i][c0 + j] = make_float2(mr[i][j] * sc, mi[i][j] * sc);
    }
    __syncthreads();

    // ---- MLP per (kh, n) ----
    float2* sM2 = (float2*)&sD[0][0];   // [32][66]
    {
        int kh = tid >> 3, n = tid & 7;
        float xr[8], xi[8];
#pragma unroll
        for (int i = 0; i < 8; ++i) {
            float2 v = sM[kh][n * 8 + i];
            xr[i] = v.x; xi[i] = v.y;
        }
        float o1r[8], o1i[8];
#pragma unroll
        for (int o = 0; o < 8; ++o) {
            float br = sb1[n * 8 + o], bi = sb1[64 + n * 8 + o];
            float sr = br - bi, si = br + bi;
#pragma unroll
            for (int i = 0; i < 8; ++i) {
                float wr = sW[0][(i * 8 + o) * 8 + n];
                float wi = sW[1][(i * 8 + o) * 8 + n];
                sr += xr[i] * wr - xi[i] * wi;
                si += xi[i] * wr + xr[i] * wi;
            }
            o1r[o] = gelu_exact(sr);
            o1i[o] = gelu_exact(si);
        }
#pragma unroll
        for (int o = 0; o < 8; ++o) {
            float br = sb2[n * 8 + o], bi = sb2[64 + n * 8 + o];
            float sr = br - bi, si = br + bi;
#pragma unroll
            for (int i = 0; i < 8; ++i) {
                float wr = sW[2][(i * 8 + o) * 8 + n];
                float wi = sW[3][(i * 8 + o) * 8 + n];
                sr += o1r[i] * wr - o1i[i] * wi;
                si += o1i[i] * wr + o1r[i] * wi;
            }
            sM2[kh * 66 + n * 8 + o] = make_float2(sr, si);
        }
    }
    __syncthreads();

    // ---- out[h][c] = sum_kh conj(T[h][kh]) * M2[kh][c], tile 4h x 4c ----
    {
        int h0 = (tid >> 4) * 4;
        int c0 = (tid & 15) * 4;
        float orr[4][4], oii[4][4];
#pragma unroll
        for (int i = 0; i < 4; ++i)
#pragma unroll
            for (int j = 0; j < 4; ++j) { orr[i][j] = 0.f; oii[i][j] = 0.f; }
        for (int kh = 0; kh < 32; ++kh) {
            float2 T0 = sT[h0 + 0][kh];
            float2 T1 = sT[h0 + 1][kh];
            float2 T2 = sT[h0 + 2][kh];
            float2 T3 = sT[h0 + 3][kh];
            float Tr[4] = {T0.x, T1.x, T2.x, T3.x};
            float Ti[4] = {T0.y, T1.y, T2.y, T3.y};
            const float4* tM = (const float4*)(sM2 + kh * 66 + c0);
            float4 m0 = tM[0], m1 = tM[1];
            float Mr[4] = {m0.x, m0.z, m1.x, m1.z};
            float Mi[4] = {m0.y, m0.w, m1.y, m1.w};
#pragma unroll
            for (int i = 0; i < 4; ++i)
#pragma unroll
                for (int j = 0; j < 4; ++j) {
                    orr[i][j] += Tr[i] * Mr[j] + Ti[i] * Mi[j];
                    oii[i][j] += Tr[i] * Mi[j] - Ti[i] * Mr[j];
                }
        }
        float2* dst = (float2*)z2f + (size_t)((b * 8 + kl) * 32 + kw) * 4096;
#pragma unroll
        for (int i = 0; i < 4; ++i) {
            float4* d4 = (float4*)(dst + (h0 + i) * 64 + c0);
            d4[0] = make_float4(orr[i][0], oii[i][0], orr[i][1], oii[i][1]);
            d4[1] = make_float4(orr[i][2], oii[i][2], orr[i][3], oii[i][3]);
        }
    }
}

// ===========================================================================
// K3: fused iDFT-W + iDFT-L + residual.  Block = (b, h, ch); 1024 threads.
// Stage z2 slab [kl][kw][cp] (64 KB) in LDS; thread (w, cp) computes its
// zW[kl] (8 x float4 registers) by reduction over kw, then does the L-inverse
// (numpy irfft: Im(kl=0) dropped, modes 1..7 doubled) + residual, streaming.
__global__ void __launch_bounds__(1024) k3_wl(const float* __restrict__ x,
                                              const float* __restrict__ z2f,
                                              float* __restrict__ outp) {
    __shared__ float2 tw[64];
    __shared__ float4 sZ[8 * 32 * 16];   // 64 KB, [kl][kw][cp]
    int tid = threadIdx.x;
    int bid = blockIdx.x;
    int b = bid >> 7, h = (bid >> 1) & 63, ch = bid & 1;
    int c0 = ch * 32;

    if (tid < 64) {
        float s, c;
        sincosf(PI2_64 * (float)tid, &s, &c);
        tw[tid] = make_float2(c, s);
    }
    const float4* z2 = (const float4*)z2f;
#pragma unroll
    for (int k = 0; k < 4; ++k) {
        int idx = k * 1024 + tid;        // 0..4095 = klkw*16 + cp
        int klkw = idx >> 4, cp = idx & 15;
        sZ[idx] = z2[(size_t)((b * 256 + klkw) * 64 + h) * 32 + ch * 16 + cp];
    }
    __syncthreads();

    int cp = tid & 15, w = tid >> 4;

    // ---- iDFT-W into registers: zW[kl] = sum_kw e^{+2pi i kw w/64} * Z ----
    float4 zw[8];
#pragma unroll
    for (int kl = 0; kl < 8; ++kl) zw[kl] = make_float4(0.f, 0.f, 0.f, 0.f);
    for (int kw = 0; kw < 32; ++kw) {
        float2 u = tw[(kw * w) & 63];    // (cos, +sin)
#pragma unroll
        for (int kl = 0; kl < 8; ++kl) {
            float4 d = sZ[(kl * 32 + kw) * 16 + cp];
            zw[kl].x += d.x * u.x - d.y * u.y;
            zw[kl].y += d.y * u.x + d.x * u.y;
            zw[kl].z += d.z * u.x - d.w * u.y;
            zw[kl].w += d.w * u.x + d.z * u.y;
        }
    }

    // ---- iDFT-L + residual, streaming over l ----
    const float* xp = x + ((size_t)((b * 64 + h) * 64 + w) * 64) * 64 + c0 + 2 * cp;
    float* op = outp + ((size_t)((b * 64 + h) * 64 + w) * 64) * 64 + c0 + 2 * cp;
    const float sc = 1.0f / 512.0f;
    for (int l = 0; l < 64; ++l) {
        float s0 = zw[0].x;
        float s1 = zw[0].z;
#pragma unroll
        for (int kl = 1; kl < 8; ++kl) {
            float2 t = tw[(l * kl) & 63];
            s0 += 2.0f * (zw[kl].x * t.x - zw[kl].y * t.y);
            s1 += 2.0f * (zw[kl].z * t.x - zw[kl].w * t.y);
        }
        float2 xv = *(const float2*)(xp + l * 64);
        *(float2*)(op + l * 64) = make_float2(s0 * sc + xv.x, s1 * sc + xv.y);
    }
}

// ===========================================================================
extern "C" void kernel_launch(void* const* d_in, const int* in_sizes, int n_in,
                              void* d_out, int out_size, void* d_ws, size_t ws_size,
                              hipStream_t stream) {
    const float* x     = (const float*)d_in[0];
    const float* w1    = (const float*)d_in[1];
    const float* b1    = (const float*)d_in[2];
    const float* w2    = (const float*)d_in[3];
    const float* b2    = (const float*)d_in[4];
    const float* la1rA = (const float*)d_in[5];
    const float* la1rB = (const float*)d_in[6];
    const float* la1iA = (const float*)d_in[7];
    const float* la1iB = (const float*)d_in[8];
    const float* la2rA = (const float*)d_in[9];
    const float* la2rB = (const float*)d_in[10];
    const float* la2iA = (const float*)d_in[11];
    const float* la2iB = (const float*)d_in[12];
    float* out = (float*)d_out;

    float* ws = (float*)d_ws;
    float* y2 = ws;                    // [4][8][32][64][64] complex = 16 MB
    float* z2 = ws + 4194304;          // same, 16 MB

    hipLaunchKernelGGL(k1_lw,    dim3(512),  dim3(1024), 0, stream, x, y2);
    hipLaunchKernelGGL(kc_h_mlp, dim3(1024), dim3(256),  0, stream, y2, z2,
                       w1, b1, w2, b2, la1rA, la1rB, la1iA, la1iB,
                       la2rA, la2rB, la2iA, la2iB);
    hipLaunchKernelGGL(k3_wl,    dim3(512),  dim3(1024), 0, stream, x, z2, out);
}